// Round 24
// baseline (318.295 us; speedup 1.0000x reference)
//
#include <hip/hip_runtime.h>

typedef short short8 __attribute__((ext_vector_type(8)));
typedef float f32x4 __attribute__((ext_vector_type(4)));
typedef float f32x2 __attribute__((ext_vector_type(2)));
typedef unsigned int uint;

#define C_IN  128
#define H_IN  112
#define W_IN  112
#define K_OUT 256
#define H_OUTD 110
#define W_OUTD 110
#define NBATCH 32

// F2 layout: [S(36)][wm(4)][mt(4)][lane(64)][e(8)], S = ph*18 + rs*2 + ch2
//   k = wm*64+mt*16+(lane&15) ; c = ph*64 + ch2*32 + (lane>>4)*8 + e
#define F_ELEMS  (36*4*4*64*8)             // 294,912

__device__ __forceinline__ unsigned short f2bf(float f) {
  uint u = __float_as_uint(f);
  u += 0x7fffu + ((u >> 16) & 1u);   // RNE
  return (unsigned short)(u >> 16);
}

// hardware packed f32x2 -> bf16x2 (RNE), single VALU instr
__device__ __forceinline__ uint cvt_pk_bf16(float lo, float hi) {
  uint v;
  asm("v_cvt_pk_bf16_f32 %0, %1, %2" : "=v"(v) : "v"(lo), "v"(hi));
  return v;
}

// ---- prep: filt (OIHW f32) -> F2 fragment-packed bf16 (ph-major slices) ----
__global__ __launch_bounds__(256) void fprep_kernel(const float* __restrict__ ft,
                                                    unsigned short* __restrict__ F) {
  int idx = blockIdx.x*256 + threadIdx.x;   // < 294912
  int e    = idx & 7;
  int lane = (idx >> 3) & 63;
  int mt   = (idx >> 9) & 3;
  int wm   = (idx >> 11) & 3;
  int S    = idx >> 13;                     // 0..35
  int ph   = S >= 18;
  int j    = S - ph*18;
  int rs   = j >> 1;
  int ch2  = j & 1;
  int k = wm*64 + mt*16 + (lane & 15);
  int c = ph*64 + ch2*32 + (lane >> 4)*8 + e;
  F[idx] = f2bf(ft[(k*C_IN + c)*9 + rs]);
}

// ---------------- fused implicit-GEMM conv, 4h x 32w tiles (full-line writes) ----------
// block: 256 thr (4 waves, 4M x 1N), output tile = 256 K_out x (4h x 32w = 128px)
// wave = 64k x 128px (4 mt x 8 nt of 16x16x32; nt = (whalf<<2)|hh), acc = 128 regs.
// 32-px output rows -> aligned 128B FULL-LINE stores (R23 counter evidence:
// WRITE_SIZE 1.2x ideal from cross-block 64B partial lines at 16w tiles).
// Halo 6h x 34w: best staging efficiency tried (1.59 cells/px).
// Prologue stages halo from x (f32 NCHW) via cvt_pk_bf16 + swizzled ds_write.
// smX [ph(2)][cell(204)][64] = 52,224 B -> 2 blocks/CU. NO barriers in K-loop;
// both operand streams reg-double-buffered; conflict-free 16x16 maps.
__global__ __launch_bounds__(256, 2) void conv_gemm(const float* __restrict__ x,
                                                    const unsigned short* __restrict__ F,
                                                    float* __restrict__ out) {
  __shared__ unsigned short smX[2*204*64];    // 52,224 B
  // bijective XCD swizzle: 3584 blocks = 8 XCDs x 448
  const int bid  = blockIdx.y*112 + blockIdx.x;
  const int wgid = (bid & 7)*448 + (bid >> 3);
  const int tile = wgid % 112;                // 28 h-tiles x 4 w-tiles
  const int n    = wgid / 112;
  const int tid  = threadIdx.x;
  const int lane = tid & 63;
  const int wm   = tid >> 6;                  // 0..3 (M quadrant, 64 k each)
  const int l15  = lane & 15;
  const int lhi  = lane >> 4;                 // 0..3
  const int th   = tile >> 2;
  const int tw   = tile & 3;
  const int h0   = th*4;
  const int w0   = tw*32;

  int browb[8];
  #pragma unroll
  for (int nt = 0; nt < 8; ++nt)
    browb[nt] = ((nt & 3)*34 + (nt >> 2)*16 + l15)*64;   // halo cell * 64 shorts

  f32x4 acc[4][8];
  #pragma unroll
  for (int mt = 0; mt < 4; ++mt)
    #pragma unroll
    for (int nt = 0; nt < 8; ++nt)
      acc[mt][nt] = (f32x4){0.f, 0.f, 0.f, 0.f};

  // per-wave A base; slice stride 8192 shorts
  const unsigned short* Aw = F + wm*2048 + lane*8;
  short8 aP[4], aQ[4], bP[8], bQ[8];

  // prefetch a(0) first: its L2 latency hides under the staging below
  #pragma unroll
  for (int u = 0; u < 4; ++u)
    aP[u] = *(const short8*)(Aw + u*512);

  // ---- fused halo staging: x (f32 NCHW) -> swizzled bf16 smX ----
  // 384 row-tasks: hh(6) x cpair(64); each = 34 floats x 2 channels
  {
    const float* xb = x + (size_t)n*C_IN*H_IN*W_IN;
    const bool tail = (w0 == 96);             // only 16 valid cols; rest clamped
    #pragma unroll
    for (int rep = 0; rep < 2; ++rep) {
      int r = rep*256 + tid;
      if (r < 384) {
        int hh = r >> 6;                      // 0..5
        int cp = r & 63;
        int c0 = cp*2;
        int hc = h0 + hh; if (hc > 111) hc = 111;
        const float* p0 = xb + ((size_t)c0*H_IN + hc)*W_IN + w0;
        const float* p1 = p0 + H_IN*W_IN;
        f32x4 r0[8], r1[8];
        #pragma unroll
        for (int q = 0; q < 8; ++q) {
          int qo = (tail && q > 3) ? 3 : q;   // clamp (feeds only discarded cols)
          r0[q] = *(const f32x4*)(p0 + qo*4);
          r1[q] = *(const f32x4*)(p1 + qo*4);
        }
        int to = tail ? 12 : 32;
        f32x2 t0 = *(const f32x2*)(p0 + to);
        f32x2 t1 = *(const f32x2*)(p1 + to);
        const int cin = c0 & 63;
        unsigned short* dst = smX + (c0 >> 6)*13056 + hh*2176;   // 34*64=2176
        #pragma unroll
        for (int j = 0; j < 34; ++j) {
          float f0 = (j < 32) ? r0[j >> 2][j & 3] : t0[j - 32];
          float f1 = (j < 32) ? r1[j >> 2][j & 3] : t1[j - 32];
          uint key   = ((uint)j & 7u) << 3;   // w0 is 32-aligned -> key depends on j only
          uint inner = (uint)cin ^ key;
          *(uint*)&dst[j*64 + inner] = cvt_pk_bf16(f0, f1);
        }
      }
    }
  }
  __syncthreads();   // only barrier: halo staged

  auto BOFF = [&](int S) {
    const int ph  = (S >= 18);
    const int jj  = S - ph*18;
    const int rs  = jj >> 1, ch2 = jj & 1;
    const int r   = rs/3, s = rs - r*3;
    const int key = ((l15 + s) & 7) << 3;
    return ph*13056 + (r*34 + s)*64 + ((ch2*32 + lhi*8) ^ key);
  };

  {
    const int boff = BOFF(0);
    #pragma unroll
    for (int nt = 0; nt < 8; ++nt)
      bP[nt] = *(const short8*)&smX[browb[nt] + boff];
  }

#define MFMAS(A, B)                                                              \
  {                                                                              \
    __builtin_amdgcn_s_setprio(1);                                               \
    _Pragma("unroll")                                                            \
    for (int nt = 0; nt < 8; ++nt) {                                             \
      _Pragma("unroll")                                                          \
      for (int mt = 0; mt < 4; ++mt)                                             \
        acc[mt][nt] = __builtin_amdgcn_mfma_f32_16x16x32_bf16(A[mt], B[nt], acc[mt][nt], 0, 0, 0); \
    }                                                                            \
    __builtin_amdgcn_s_setprio(0);                                               \
  }

  for (int i = 0; i < 36; i += 2) {
    {
      const unsigned short* As = Aw + (size_t)(i + 1)*8192;
      #pragma unroll
      for (int u = 0; u < 4; ++u)
        aQ[u] = *(const short8*)(As + u*512);
      const int boff = BOFF(i + 1);
      #pragma unroll
      for (int nt = 0; nt < 8; ++nt)
        bQ[nt] = *(const short8*)&smX[browb[nt] + boff];
    }
    MFMAS(aP, bP);
    if (i + 2 < 36) {
      const unsigned short* As = Aw + (size_t)(i + 2)*8192;
      #pragma unroll
      for (int u = 0; u < 4; ++u)
        aP[u] = *(const short8*)(As + u*512);
      const int boff = BOFF(i + 2);
      #pragma unroll
      for (int nt = 0; nt < 8; ++nt)
        bP[nt] = *(const short8*)&smX[browb[nt] + boff];
    }
    MFMAS(aQ, bQ);
  }
#undef MFMAS

  // epilogue: D frag: col(px)=l15 within half, row(k)=lhi*4+reg
  #pragma unroll
  for (int nt = 0; nt < 8; ++nt) {
    int hv = h0 + (nt & 3);
    int wv = w0 + (nt >> 2)*16 + l15;
    if (hv < H_OUTD && wv < W_OUTD) {
      float* po = out + (size_t)n*K_OUT*(H_OUTD*W_OUTD) + hv*W_OUTD + wv;
      #pragma unroll
      for (int mt = 0; mt < 4; ++mt) {
        #pragma unroll
        for (int reg = 0; reg < 4; ++reg) {
          int k = wm*64 + mt*16 + lhi*4 + reg;
          po[(size_t)k*(H_OUTD*W_OUTD)] = acc[mt][nt][reg];
        }
      }
    }
  }
}

// ---------------- fallback (ws too small): naive fp32 ----------------
__global__ void naive_conv(const float* __restrict__ x, const float* __restrict__ ft,
                           float* __restrict__ out) {
  int idx = blockIdx.x*256 + threadIdx.x;
  int total = NBATCH*K_OUT*H_OUTD*W_OUTD;
  if (idx >= total) return;
  int w = idx % W_OUTD; int t = idx / W_OUTD;
  int h = t % H_OUTD; t /= H_OUTD;
  int k = t % K_OUT; int nn = t / K_OUT;
  float acc = 0.f;
  for (int c = 0; c < C_IN; ++c)
    for (int r = 0; r < 3; ++r)
      for (int s = 0; s < 3; ++s)
        acc += x[((size_t)(nn*C_IN + c)*H_IN + h + r)*W_IN + w + s]
             * ft[((k*C_IN + c)*3 + r)*3 + s];
  out[idx] = acc;
}

extern "C" void kernel_launch(void* const* d_in, const int* in_sizes, int n_in,
                              void* d_out, int out_size, void* d_ws, size_t ws_size,
                              hipStream_t stream) {
  (void)in_sizes; (void)n_in; (void)out_size;
  const float* x  = (const float*)d_in[0];
  const float* ft = (const float*)d_in[1];
  float* out = (float*)d_out;
  size_t need = (size_t)F_ELEMS * sizeof(unsigned short);
  if (ws_size >= need) {
    unsigned short* F = (unsigned short*)d_ws;
    fprep_kernel<<<dim3(1152), 256, 0, stream>>>(ft, F);
    conv_gemm<<<dim3(112, 32), 256, 0, stream>>>(x, F, out);
  } else {
    int total = NBATCH*K_OUT*H_OUTD*W_OUTD;
    naive_conv<<<(total + 255)/256, 256, 0, stream>>>(x, ft, out);
  }
}

// Round 25
// 292.706 us; speedup vs baseline: 1.0874x; 1.0874x over previous
//
#include <hip/hip_runtime.h>

typedef short short8 __attribute__((ext_vector_type(8)));
typedef float f32x4 __attribute__((ext_vector_type(4)));
typedef float f32x2 __attribute__((ext_vector_type(2)));
typedef unsigned int uint;

#define C_IN  128
#define H_IN  112
#define W_IN  112
#define K_OUT 256
#define H_OUTD 110
#define W_OUTD 110
#define NBATCH 32

// F2 layout: [S(36)][wm(4)][mt(4)][lane(64)][e(8)], S = ph*18 + rs*2 + ch2
//   k = wm*64+mt*16+(lane&15) ; c = ph*64 + ch2*32 + (lane>>4)*8 + e
#define F_ELEMS  (36*4*4*64*8)             // 294,912

__device__ __forceinline__ unsigned short f2bf(float f) {
  uint u = __float_as_uint(f);
  u += 0x7fffu + ((u >> 16) & 1u);   // RNE
  return (unsigned short)(u >> 16);
}

// hardware packed f32x2 -> bf16x2 (RNE), single VALU instr
__device__ __forceinline__ uint cvt_pk_bf16(float lo, float hi) {
  uint v;
  asm("v_cvt_pk_bf16_f32 %0, %1, %2" : "=v"(v) : "v"(lo), "v"(hi));
  return v;
}

// ---- prep: filt (OIHW f32) -> F2 fragment-packed bf16 (ph-major slices) ----
__global__ __launch_bounds__(256) void fprep_kernel(const float* __restrict__ ft,
                                                    unsigned short* __restrict__ F) {
  int idx = blockIdx.x*256 + threadIdx.x;   // < 294912
  int e    = idx & 7;
  int lane = (idx >> 3) & 63;
  int mt   = (idx >> 9) & 3;
  int wm   = (idx >> 11) & 3;
  int S    = idx >> 13;                     // 0..35
  int ph   = S >= 18;
  int j    = S - ph*18;
  int rs   = j >> 1;
  int ch2  = j & 1;
  int k = wm*64 + mt*16 + (lane & 15);
  int c = ph*64 + ch2*32 + (lane >> 4)*8 + e;
  F[idx] = f2bf(ft[(k*C_IN + c)*9 + rs]);
}

// ---------------- fused implicit-GEMM conv (transpose folded into prologue) -------------
// block: 256 thr (4 waves, 4M x 1N), output tile = 256 K_out x (4h x 16w = 64px)
// wave = 64k x 64px (4 mt x 4 nt of 16x16x32), acc = 64 regs -> 3 blocks/CU.
// Prologue stages halo DIRECTLY from x (f32 NCHW) via v_cvt_pk_bf16_f32
// + packed-b32 ds_write into swizzled smX (2-way banks = free).
// smX [ph(2)][cell(108)][64] = 27,648 B. NO barriers in K-loop; both operand
// streams reg-double-buffered; conflict-free 16x16 fragment maps.
// FINAL (R24): best stable configuration after 24 rounds. Neutral/negative:
// 8-phase, counted-vmcnt, persistent, phase-split, 32x32 MFMA, 3-wave TLP,
// L2-A halving, write re-tiling (440B output rows make line-aligned stores
// impossible). Fusion + cvt_pk + this geometry = best.
__global__ __launch_bounds__(256, 3) void conv_gemm(const float* __restrict__ x,
                                                    const unsigned short* __restrict__ F,
                                                    float* __restrict__ out) {
  __shared__ unsigned short smX[2*108*64];    // 27,648 B
  // bijective chunked XCD swizzle: 6272 blocks = 8 XCDs x 784
  const int bid  = blockIdx.y*196 + blockIdx.x;
  const int wgid = (bid & 7)*784 + (bid >> 3);
  const int tile = wgid % 196;                // 28 h-tiles x 7 w-tiles
  const int n    = wgid / 196;
  const int tid  = threadIdx.x;
  const int lane = tid & 63;
  const int wm   = tid >> 6;                  // 0..3 (M quadrant, 64 k each)
  const int l15  = lane & 15;
  const int lhi  = lane >> 4;                 // 0..3
  const int th   = tile / 7;
  const int tw   = tile - th*7;
  const int h0   = th*4;
  const int w0   = tw*16;

  int browb[4];
  #pragma unroll
  for (int nt = 0; nt < 4; ++nt)
    browb[nt] = (nt*18 + l15)*64;             // halo cell * 64 shorts

  f32x4 acc[4][4];
  #pragma unroll
  for (int mt = 0; mt < 4; ++mt)
    #pragma unroll
    for (int nt = 0; nt < 4; ++nt)
      acc[mt][nt] = (f32x4){0.f, 0.f, 0.f, 0.f};

  // per-wave A base; slice stride 8192 shorts
  const unsigned short* Aw = F + wm*2048 + lane*8;
  short8 aP[4], aQ[4], bP[4], bQ[4];

  // prefetch a(0) first: its L2 latency hides under the staging below
  #pragma unroll
  for (int u = 0; u < 4; ++u)
    aP[u] = *(const short8*)(Aw + u*512);

  // ---- fused halo staging: x (f32 NCHW) -> swizzled bf16 smX ----
  // rows: r = hh*64 + cpair (384 rows of 18 floats x 2 channels)
  {
    const float* xb = x + (size_t)n*C_IN*H_IN*W_IN;
    const int toff = (w0 == 96) ? 12 : 16;    // tail clamp (garbage feeds only discarded cols)
    #pragma unroll
    for (int rep = 0; rep < 2; ++rep) {
      int r = rep*256 + tid;
      if (r < 384) {
        int hh = r >> 6;                      // 0..5
        int cp = r & 63;
        int c0 = cp*2;
        int hc = h0 + hh; if (hc > 111) hc = 111;
        const float* p0 = xb + ((size_t)c0*H_IN + hc)*W_IN + w0;
        const float* p1 = p0 + H_IN*W_IN;
        f32x4 r0[4], r1[4];
        #pragma unroll
        for (int q = 0; q < 4; ++q) {
          r0[q] = *(const f32x4*)(p0 + q*4);
          r1[q] = *(const f32x4*)(p1 + q*4);
        }
        f32x2 t0 = *(const f32x2*)(p0 + toff);
        f32x2 t1 = *(const f32x2*)(p1 + toff);
        const int cin = c0 & 63;
        unsigned short* dst = smX + (c0 >> 6)*6912 + hh*18*64;
        #pragma unroll
        for (int j = 0; j < 18; ++j) {
          float f0 = (j < 16) ? r0[j >> 2][j & 3] : t0[j - 16];
          float f1 = (j < 16) ? r1[j >> 2][j & 3] : t1[j - 16];
          uint key   = ((uint)j & 7u) << 3;   // w0 is 16-aligned -> key depends on j only
          uint inner = (uint)cin ^ key;
          *(uint*)&dst[j*64 + inner] = cvt_pk_bf16(f0, f1);
        }
      }
    }
  }
  __syncthreads();   // only barrier: halo staged

  auto BOFF = [&](int S) {
    const int ph  = (S >= 18);
    const int jj  = S - ph*18;
    const int rs  = jj >> 1, ch2 = jj & 1;
    const int r   = rs/3, s = rs - r*3;
    const int key = ((l15 + s) & 7) << 3;
    return ph*6912 + (r*18 + s)*64 + ((ch2*32 + lhi*8) ^ key);
  };

  {
    const int boff = BOFF(0);
    #pragma unroll
    for (int nt = 0; nt < 4; ++nt)
      bP[nt] = *(const short8*)&smX[browb[nt] + boff];
  }

#define MFMAS(A, B)                                                              \
  {                                                                              \
    __builtin_amdgcn_s_setprio(1);                                               \
    _Pragma("unroll")                                                            \
    for (int nt = 0; nt < 4; ++nt) {                                             \
      _Pragma("unroll")                                                          \
      for (int mt = 0; mt < 4; ++mt)                                             \
        acc[mt][nt] = __builtin_amdgcn_mfma_f32_16x16x32_bf16(A[mt], B[nt], acc[mt][nt], 0, 0, 0); \
    }                                                                            \
    __builtin_amdgcn_s_setprio(0);                                               \
  }

  for (int i = 0; i < 36; i += 2) {
    {
      const unsigned short* As = Aw + (size_t)(i + 1)*8192;
      #pragma unroll
      for (int u = 0; u < 4; ++u)
        aQ[u] = *(const short8*)(As + u*512);
      const int boff = BOFF(i + 1);
      #pragma unroll
      for (int nt = 0; nt < 4; ++nt)
        bQ[nt] = *(const short8*)&smX[browb[nt] + boff];
    }
    MFMAS(aP, bP);
    if (i + 2 < 36) {
      const unsigned short* As = Aw + (size_t)(i + 2)*8192;
      #pragma unroll
      for (int u = 0; u < 4; ++u)
        aP[u] = *(const short8*)(As + u*512);
      const int boff = BOFF(i + 2);
      #pragma unroll
      for (int nt = 0; nt < 4; ++nt)
        bP[nt] = *(const short8*)&smX[browb[nt] + boff];
    }
    MFMAS(aQ, bQ);
  }
#undef MFMAS

  // epilogue: D frag: col(px)=l15, row(k)=lhi*4+reg
  const int wv = w0 + l15;
  #pragma unroll
  for (int nt = 0; nt < 4; ++nt) {
    int hv = h0 + nt;
    if (hv < H_OUTD && wv < W_OUTD) {
      float* po = out + (size_t)n*K_OUT*(H_OUTD*W_OUTD) + hv*W_OUTD + wv;
      #pragma unroll
      for (int mt = 0; mt < 4; ++mt) {
        #pragma unroll
        for (int reg = 0; reg < 4; ++reg) {
          int k = wm*64 + mt*16 + lhi*4 + reg;
          po[(size_t)k*(H_OUTD*W_OUTD)] = acc[mt][nt][reg];
        }
      }
    }
  }
}

// ---------------- fallback (ws too small): naive fp32 ----------------
__global__ void naive_conv(const float* __restrict__ x, const float* __restrict__ ft,
                           float* __restrict__ out) {
  int idx = blockIdx.x*256 + threadIdx.x;
  int total = NBATCH*K_OUT*H_OUTD*W_OUTD;
  if (idx >= total) return;
  int w = idx % W_OUTD; int t = idx / W_OUTD;
  int h = t % H_OUTD; t /= H_OUTD;
  int k = t % K_OUT; int nn = t / K_OUT;
  float acc = 0.f;
  for (int c = 0; c < C_IN; ++c)
    for (int r = 0; r < 3; ++r)
      for (int s = 0; s < 3; ++s)
        acc += x[((size_t)(nn*C_IN + c)*H_IN + h + r)*W_IN + w + s]
             * ft[((k*C_IN + c)*3 + r)*3 + s];
  out[idx] = acc;
}

extern "C" void kernel_launch(void* const* d_in, const int* in_sizes, int n_in,
                              void* d_out, int out_size, void* d_ws, size_t ws_size,
                              hipStream_t stream) {
  (void)in_sizes; (void)n_in; (void)out_size;
  const float* x  = (const float*)d_in[0];
  const float* ft = (const float*)d_in[1];
  float* out = (float*)d_out;
  size_t need = (size_t)F_ELEMS * sizeof(unsigned short);
  if (ws_size >= need) {
    unsigned short* F = (unsigned short*)d_ws;
    fprep_kernel<<<dim3(1152), 256, 0, stream>>>(ft, F);
    conv_gemm<<<dim3(196, 32), 256, 0, stream>>>(x, F, out);
  } else {
    int total = NBATCH*K_OUT*H_OUTD*W_OUTD;
    naive_conv<<<(total + 255)/256, 256, 0, stream>>>(x, ft, out);
  }
}